// Round 8
// baseline (294.436 us; speedup 1.0000x reference)
//
#include <hip/hip_runtime.h>

// Problem constants (PointPillarScatter_Seg): B=4, P_PER=20000, C=64, NY=NX=512
constexpr int C_CH = 64;
constexpr int NY_D = 512;
constexpr int NX_D = 512;
constexpr int CELLS_PER_BATCH = NY_D * NX_D;          // 262144
constexpr int B_D = 4;
constexpr int NCELLS = B_D * CELLS_PER_BATCH;         // 1048576 = 2^20
constexpr int NQUADS = NCELLS / 4;                    // 262144  = 2^18

// ---------------------------------------------------------------------------
// Kernel 1: fill the pillar-index canvas with -1 (empty cell sentinel).
// ---------------------------------------------------------------------------
__global__ void fill_idx(int4* __restrict__ canvas4, int n4) {
    int t = blockIdx.x * blockDim.x + threadIdx.x;
    if (t < n4) canvas4[t] = make_int4(-1, -1, -1, -1);
}

// ---------------------------------------------------------------------------
// Kernel 2: scatter pillar id p into canvas[b, y, x]. Unique indices -> no races.
// ---------------------------------------------------------------------------
__global__ void scatter_idx(const int4* __restrict__ coords,
                            int* __restrict__ canvas, int P) {
    int p = blockIdx.x * blockDim.x + threadIdx.x;
    if (p < P) {
        int4 c = coords[p];  // (batch, z, y, x)
        canvas[c.x * CELLS_PER_BATCH + c.z * NX_D + c.w] = p;
    }
}

// ---------------------------------------------------------------------------
// Kernel 3: gather. 4 threads per cell-quad; each thread owns a 16-channel
// slice of 4 consecutive x cells. 2^20 threads -> 16384 waves (max occupancy)
// to hide scattered feature-read latency. Per thread: 16 float4 loads
// (4 rows x 64 B slice, fully unrolled) + 16 coalesced float4 stores via
// 4x4 register transposes. PLAIN stores: non-temporal stores broke
// post-timing validation (stale 0xAA poison lines left in L2 by the
// harness's d_out memset were not invalidated by nt stores).
// ---------------------------------------------------------------------------
__global__ void gather_out(const float* __restrict__ feat,
                           const int* __restrict__ canvas,
                           float* __restrict__ out) {
    int t = blockIdx.x * blockDim.x + threadIdx.x;   // [0, 2^20)
    int q = t & (NQUADS - 1);                        // cell quad id
    int slice = t >> 18;                             // 0..3
    int c_base = slice << 4;                         // 0,16,32,48

    int x0 = (q & (NX_D / 4 - 1)) << 2;              // 0..508 step 4
    int y  = (q >> 7) & (NY_D - 1);
    int b  = q >> 16;

    int cell = b * CELLS_PER_BATCH + y * NX_D + x0;
    int4 idx = *reinterpret_cast<const int4*>(canvas + cell);

    float* op = out + (size_t)b * (C_CH * CELLS_PER_BATCH)
                    + (size_t)c_base * CELLS_PER_BATCH + y * NX_D + x0;

    const float4 z4 = make_float4(0.f, 0.f, 0.f, 0.f);
    const float* ra = feat + (size_t)idx.x * C_CH + c_base;
    const float* rb = feat + (size_t)idx.y * C_CH + c_base;
    const float* rc = feat + (size_t)idx.z * C_CH + c_base;
    const float* rd = feat + (size_t)idx.w * C_CH + c_base;

#pragma unroll
    for (int j = 0; j < 4; ++j) {                    // 4 channels per step
        int c4 = j << 2;
        float4 fa = (idx.x >= 0) ? *reinterpret_cast<const float4*>(ra + c4) : z4;
        float4 fb = (idx.y >= 0) ? *reinterpret_cast<const float4*>(rb + c4) : z4;
        float4 fc = (idx.z >= 0) ? *reinterpret_cast<const float4*>(rc + c4) : z4;
        float4 fd = (idx.w >= 0) ? *reinterpret_cast<const float4*>(rd + c4) : z4;

        *reinterpret_cast<float4*>(op + (size_t)(c4 + 0) * CELLS_PER_BATCH) =
            make_float4(fa.x, fb.x, fc.x, fd.x);
        *reinterpret_cast<float4*>(op + (size_t)(c4 + 1) * CELLS_PER_BATCH) =
            make_float4(fa.y, fb.y, fc.y, fd.y);
        *reinterpret_cast<float4*>(op + (size_t)(c4 + 2) * CELLS_PER_BATCH) =
            make_float4(fa.z, fb.z, fc.z, fd.z);
        *reinterpret_cast<float4*>(op + (size_t)(c4 + 3) * CELLS_PER_BATCH) =
            make_float4(fa.w, fb.w, fc.w, fd.w);
    }
}

// ---------------------------------------------------------------------------
extern "C" void kernel_launch(void* const* d_in, const int* in_sizes, int n_in,
                              void* d_out, int out_size, void* d_ws, size_t ws_size,
                              hipStream_t stream) {
    const float* feat  = (const float*)d_in[0];          // [P, 64] fp32
    const int*  coords = (const int*)d_in[1];            // [P, 4] int32
    float* out = (float*)d_out;                          // [B, 64, 512, 512] fp32

    const int P = in_sizes[1] / 4;                       // 80000

    int* canvas = (int*)d_ws;                            // NCELLS int32 = 4 MB

    // 1) fill index canvas with -1
    fill_idx<<<(NCELLS / 4 + 255) / 256, 256, 0, stream>>>((int4*)canvas,
                                                           NCELLS / 4);
    // 2) scatter pillar ids
    scatter_idx<<<(P + 255) / 256, 256, 0, stream>>>(
        (const int4*)coords, canvas, P);
    // 3) gather + write output (coalesced, 4 channel-slices per cell quad)
    {
        int nt = NQUADS * 4;                             // 2^20 threads
        gather_out<<<nt / 256, 256, 0, stream>>>(feat, canvas, out);
    }
}

// Round 9
// 287.292 us; speedup vs baseline: 1.0249x; 1.0249x over previous
//
#include <hip/hip_runtime.h>

// Problem constants (PointPillarScatter_Seg): B=4, P_PER=20000, C=64, NY=NX=512
constexpr int C_CH = 64;
constexpr int NY_D = 512;
constexpr int NX_D = 512;
constexpr int CELLS_PER_BATCH = NY_D * NX_D;          // 262144
constexpr int B_D = 4;
constexpr int NCELLS = B_D * CELLS_PER_BATCH;         // 1048576 = 2^20
constexpr int NQUADS = NCELLS / 4;                    // 262144  = 2^18

// ---------------------------------------------------------------------------
// Kernel 1: fill the pillar-index canvas with -1 (empty cell sentinel).
// ---------------------------------------------------------------------------
__global__ void fill_idx(int4* __restrict__ canvas4, int n4) {
    int t = blockIdx.x * blockDim.x + threadIdx.x;
    if (t < n4) canvas4[t] = make_int4(-1, -1, -1, -1);
}

// ---------------------------------------------------------------------------
// Kernel 2: scatter pillar id p into canvas[b, y, x]  AND warm feat into L2.
// Each thread reads its pillar's full 256 B feature row (4x float4, fully
// coalesced: wave covers 16 KB contiguous) and keeps it live via asm volatile
// (prevents DCE). 20 MB total -> fits aggregate 32 MB L2, so the gather's
// otherwise-random 64 B feature reads become L2 hits and the HBM channels
// are left to the streaming 268 MB write.
// ---------------------------------------------------------------------------
__global__ void scatter_idx(const int4* __restrict__ coords,
                            const float* __restrict__ feat,
                            int* __restrict__ canvas, int P) {
    int p = blockIdx.x * blockDim.x + threadIdx.x;
    if (p < P) {
        int4 c = coords[p];  // (batch, z, y, x)
        canvas[c.x * CELLS_PER_BATCH + c.z * NX_D + c.w] = p;

        const float4* row = reinterpret_cast<const float4*>(feat + (size_t)p * C_CH);
        float4 f0 = row[0], f1 = row[1], f2 = row[2], f3 = row[3];
        float4 f4 = row[4], f5 = row[5], f6 = row[6], f7 = row[7];
        float4 f8 = row[8], f9 = row[9], fa = row[10], fb = row[11];
        float4 fc = row[12], fd = row[13], fe = row[14], ff = row[15];
        // consume every component so the dwordx4 loads are kept whole
        float s = f0.x + f0.y + f0.z + f0.w + f1.x + f1.y + f1.z + f1.w
                + f2.x + f2.y + f2.z + f2.w + f3.x + f3.y + f3.z + f3.w
                + f4.x + f4.y + f4.z + f4.w + f5.x + f5.y + f5.z + f5.w
                + f6.x + f6.y + f6.z + f6.w + f7.x + f7.y + f7.z + f7.w
                + f8.x + f8.y + f8.z + f8.w + f9.x + f9.y + f9.z + f9.w
                + fa.x + fa.y + fa.z + fa.w + fb.x + fb.y + fb.z + fb.w
                + fc.x + fc.y + fc.z + fc.w + fd.x + fd.y + fd.z + fd.w
                + fe.x + fe.y + fe.z + fe.w + ff.x + ff.y + ff.z + ff.w;
        asm volatile("" :: "v"(s));
    }
}

// ---------------------------------------------------------------------------
// Kernel 3: gather. 4 threads per cell-quad; each thread owns a 16-channel
// slice of 4 consecutive x cells. 2^20 threads -> 16384 waves. Per thread:
// 16 float4 loads (mostly L2-hit after the scatter-phase warm) + 16
// coalesced float4 stores via 4x4 register transposes. PLAIN stores:
// non-temporal stores broke post-timing validation (stale 0xAA poison
// lines in L2 were not invalidated by nt stores).
// ---------------------------------------------------------------------------
__global__ void gather_out(const float* __restrict__ feat,
                           const int* __restrict__ canvas,
                           float* __restrict__ out) {
    int t = blockIdx.x * blockDim.x + threadIdx.x;   // [0, 2^20)
    int q = t & (NQUADS - 1);                        // cell quad id
    int slice = t >> 18;                             // 0..3
    int c_base = slice << 4;                         // 0,16,32,48

    int x0 = (q & (NX_D / 4 - 1)) << 2;              // 0..508 step 4
    int y  = (q >> 7) & (NY_D - 1);
    int b  = q >> 16;

    int cell = b * CELLS_PER_BATCH + y * NX_D + x0;
    int4 idx = *reinterpret_cast<const int4*>(canvas + cell);

    float* op = out + (size_t)b * (C_CH * CELLS_PER_BATCH)
                    + (size_t)c_base * CELLS_PER_BATCH + y * NX_D + x0;

    const float4 z4 = make_float4(0.f, 0.f, 0.f, 0.f);
    const float* ra = feat + (size_t)idx.x * C_CH + c_base;
    const float* rb = feat + (size_t)idx.y * C_CH + c_base;
    const float* rc = feat + (size_t)idx.z * C_CH + c_base;
    const float* rd = feat + (size_t)idx.w * C_CH + c_base;

#pragma unroll
    for (int j = 0; j < 4; ++j) {                    // 4 channels per step
        int c4 = j << 2;
        float4 fa = (idx.x >= 0) ? *reinterpret_cast<const float4*>(ra + c4) : z4;
        float4 fb = (idx.y >= 0) ? *reinterpret_cast<const float4*>(rb + c4) : z4;
        float4 fc = (idx.z >= 0) ? *reinterpret_cast<const float4*>(rc + c4) : z4;
        float4 fd = (idx.w >= 0) ? *reinterpret_cast<const float4*>(rd + c4) : z4;

        *reinterpret_cast<float4*>(op + (size_t)(c4 + 0) * CELLS_PER_BATCH) =
            make_float4(fa.x, fb.x, fc.x, fd.x);
        *reinterpret_cast<float4*>(op + (size_t)(c4 + 1) * CELLS_PER_BATCH) =
            make_float4(fa.y, fb.y, fc.y, fd.y);
        *reinterpret_cast<float4*>(op + (size_t)(c4 + 2) * CELLS_PER_BATCH) =
            make_float4(fa.z, fb.z, fc.z, fd.z);
        *reinterpret_cast<float4*>(op + (size_t)(c4 + 3) * CELLS_PER_BATCH) =
            make_float4(fa.w, fb.w, fc.w, fd.w);
    }
}

// ---------------------------------------------------------------------------
extern "C" void kernel_launch(void* const* d_in, const int* in_sizes, int n_in,
                              void* d_out, int out_size, void* d_ws, size_t ws_size,
                              hipStream_t stream) {
    const float* feat  = (const float*)d_in[0];          // [P, 64] fp32
    const int*  coords = (const int*)d_in[1];            // [P, 4] int32
    float* out = (float*)d_out;                          // [B, 64, 512, 512] fp32

    const int P = in_sizes[1] / 4;                       // 80000

    int* canvas = (int*)d_ws;                            // NCELLS int32 = 4 MB

    // 1) fill index canvas with -1
    fill_idx<<<(NCELLS / 4 + 255) / 256, 256, 0, stream>>>((int4*)canvas,
                                                           NCELLS / 4);
    // 2) scatter pillar ids + warm feat into L2
    scatter_idx<<<(P + 255) / 256, 256, 0, stream>>>(
        (const int4*)coords, feat, canvas, P);
    // 3) gather + write output (coalesced, 4 channel-slices per cell quad)
    {
        int nt = NQUADS * 4;                             // 2^20 threads
        gather_out<<<nt / 256, 256, 0, stream>>>(feat, canvas, out);
    }
}